// Round 11
// baseline (2347.178 us; speedup 1.0000x reference)
//
#include <hip/hip_runtime.h>
#include <cstdint>
#include <cstddef>

#define U4    512   // 4*U
#define UNITS 128
#define BATCH 256
#define TSEQ  512
#define FEAT  64
#define SEQS  8                  // sequences per lstm cell block (fills 16 A-rows)
#define NBLK  (BATCH / SEQS)     // 32 blocks per lstm cell

typedef short short8 __attribute__((ext_vector_type(8)));
typedef float f32x4  __attribute__((ext_vector_type(4)));
typedef unsigned short tab_t[16][136];

// MFMA inline asm ("a" on B keeps the AGPR-resident fragment set readable
// in place; perf-equivalent to builtin per R7/R8 but pins allocation).
#define MFMA_BF16(C, A, B) \
    asm("v_mfma_f32_16x16x32_bf16 %0, %1, %2, %0" : "+v"(C) : "v"(A), "a"(B))

// Raw barrier draining ONLY LDS (v8).
__device__ __forceinline__ void barrier_lds_only() {
    __builtin_amdgcn_sched_barrier(0);
    asm volatile("s_waitcnt lgkmcnt(0)" ::: "memory");
    __builtin_amdgcn_s_barrier();
    __builtin_amdgcn_sched_barrier(0);
}

// ---------------- fast activations (fp32, ~1e-7 rel err) ----------------
__device__ __forceinline__ float sigm(float x) {
    float e = __expf(-x);
    return __fdividef(1.0f, 1.0f + e);
}
__device__ __forceinline__ float tanh_fast(float x) {
    float e = __expf(2.0f * x);
    return 1.0f - __fdividef(2.0f, e + 1.0f);
}

// ---------------- bf16 split helpers (RNE) ----------------
__device__ __forceinline__ unsigned short f2bf(float f) {
    unsigned u = __float_as_uint(f);
    unsigned r = u + 0x7FFFu + ((u >> 16) & 1u);
    return (unsigned short)(r >> 16);
}
__device__ __forceinline__ float bf2f(unsigned short h) {
    return __uint_as_float(((unsigned)h) << 16);
}

// ---------------- R & W -> bf16 hi/lo MFMA B-fragments (fused launch) -----
// Also zeroes the 64 stage-sync counters each graph replay (block 0).
__global__ __launch_bounds__(256)
void rw_frag(const float* __restrict__ R0, const float* __restrict__ R1,
             const float* __restrict__ R2,
             const float* __restrict__ W0, const float* __restrict__ W1,
             const float* __restrict__ W2,
             unsigned short* __restrict__ Rf, unsigned short* __restrict__ Wf,
             unsigned int* __restrict__ ctrs)
{
    if (blockIdx.x == 0 && threadIdx.x < 64) ctrs[threadIdx.x] = 0;

    if (blockIdx.x < 192) {
        int gid = blockIdx.x * 256 + threadIdx.x;    // 3 * 16384
        int l    = gid >> 14;
        int r    = gid & 16383;
        int lane = r & 63;
        int fi   = r >> 6;
        int pass = fi & 1;
        int kt   = (fi >> 1) & 3;
        int gate = (fi >> 3) & 3;
        int w    = fi >> 5;
        const float* R = (l == 0) ? R0 : (l == 1) ? R1 : R2;

        int col = gate * UNITS + w * 16 + (lane & 15);
        int k0  = kt * 32 + (lane >> 4) * 8;
        short8 v;
        #pragma unroll
        for (int j = 0; j < 8; ++j) {
            float x = R[(size_t)(k0 + j) * U4 + col];
            unsigned short hi = f2bf(x);
            unsigned short s = pass ? f2bf(x - bf2f(hi)) : hi;
            v[j] = (short)s;
        }
        *(short8*)(Rf + (size_t)gid * 8) = v;
    } else {
        int gid = (blockIdx.x - 192) * 256 + threadIdx.x;
        int l    = gid >> 14;
        int r    = gid & 16383;
        int lane = r & 63;
        int fi   = r >> 6;
        int pass = fi & 1;
        int kt   = (fi >> 1) & 3;
        int nt   = fi >> 3;
        const float* W = (l == 0) ? W0 : (l == 1) ? W1 : W2;
        const int K = (l == 0) ? FEAT : UNITS;

        int col = nt * 16 + (lane & 15);
        int k0  = kt * 32 + (lane >> 4) * 8;
        short8 v;
        #pragma unroll
        for (int j = 0; j < 8; ++j) {
            float x = (k0 + j < K) ? W[(size_t)(k0 + j) * U4 + col] : 0.f;
            unsigned short hi = f2bf(x);
            unsigned short s = pass ? f2bf(x - bf2f(hi)) : hi;
            v[j] = (short)s;
        }
        *(short8*)(Wf + (size_t)gid * 8) = v;
    }
}

// ---------------- projection cell (device body) --------------------------
// packed=1: input u32 (h_hi | h_lo<<16). packed=0: fp32 (x), RNE split here.
// doneCtr != nullptr: producer role inside stage_fused -> fence + release
// increment so spinning lstm consumers (agent-scope acquire) may proceed.
struct PCell {
    const void* in;
    float* out;
    const unsigned short* wf;
    const float* bias;
    unsigned int* doneCtr;
    int sB, sT, t0, K, packed, pad_;
};
struct PStage { PCell c[1]; };

__device__ __forceinline__ void proj_body(const PCell& ce, int bx, int tcShift,
                                          tab_t* __restrict__ atab)
{
    const int tid  = threadIdx.x;
    const int lane = tid & 63;
    const int w    = tid >> 6;
    const int m    = lane & 15;
    const int quad = lane >> 4;
    const int TcMask = (1 << tcShift) - 1;
    const int m0 = bx * 64;

    short8 bf[4][4][2];
    #pragma unroll
    for (int nt = 0; nt < 4; ++nt)
        #pragma unroll
        for (int kt = 0; kt < 4; ++kt)
            #pragma unroll
            for (int pp = 0; pp < 2; ++pp)
                bf[nt][kt][pp] = *(const short8*)(
                    ce.wf + ((size_t)((((w * 4 + nt) * 4 + kt) * 2) + pp) * 64 + lane) * 8);

    if (ce.packed) {
        const unsigned int* __restrict__ inp = (const unsigned int*)ce.in;
        #pragma unroll
        for (int rep = 0; rep < 16; ++rep) {
            int idx = rep * 512 + tid;
            int row = idx >> 7;
            int k   = idx & 127;
            int rg  = m0 + row;
            int b = rg >> tcShift, tc = rg & TcMask;
            unsigned int u = inp[(size_t)b * ce.sB + (size_t)(ce.t0 + tc) * ce.sT + k];
            atab[row >> 3][2 * (row & 7)][k]     = (unsigned short)(u & 0xFFFFu);
            atab[row >> 3][2 * (row & 7) + 1][k] = (unsigned short)(u >> 16);
        }
    } else {
        const float* __restrict__ inp = (const float*)ce.in;
        #pragma unroll
        for (int rep = 0; rep < 16; ++rep) {
            int idx = rep * 512 + tid;
            int row = idx >> 7;
            int k   = idx & 127;
            int rg  = m0 + row;
            int b = rg >> tcShift, tc = rg & TcMask;
            float x = 0.f;
            if (k < ce.K)
                x = inp[(size_t)b * ce.sB + (size_t)(ce.t0 + tc) * ce.sT + k];
            unsigned short hi = f2bf(x);
            atab[row >> 3][2 * (row & 7)][k]     = hi;
            atab[row >> 3][2 * (row & 7) + 1][k] = f2bf(x - bf2f(hi));
        }
    }
    __syncthreads();

    float bb[4];
    #pragma unroll
    for (int nt = 0; nt < 4; ++nt) bb[nt] = ce.bias[w * 64 + nt * 16 + m];

    float* __restrict__ outp = ce.out;
    #pragma unroll 1
    for (int r = 0; r < 8; ++r) {
        short8 af[4];
        #pragma unroll
        for (int kt = 0; kt < 4; ++kt)
            af[kt] = *(const short8*)(&atab[r][m][kt * 32 + quad * 8]);

        f32x4 C[4];
        #pragma unroll
        for (int nt = 0; nt < 4; ++nt) C[nt] = f32x4{0.f, 0.f, 0.f, 0.f};

        #pragma unroll
        for (int kt = 0; kt < 4; ++kt)
            #pragma unroll
            for (int pp = 0; pp < 2; ++pp)
                #pragma unroll
                for (int nt = 0; nt < 4; ++nt)
                    MFMA_BF16(C[nt], af[kt], bf[nt][kt][pp]);

        int row0 = m0 + r * 8 + 2 * quad;
        #pragma unroll
        for (int nt = 0; nt < 4; ++nt) {
            float z0 = C[nt].x + C[nt].y + bb[nt];
            float z1 = C[nt].z + C[nt].w + bb[nt];
            int col = w * 64 + nt * 16 + m;
            outp[(size_t)row0 * U4 + col]       = z0;
            outp[(size_t)(row0 + 1) * U4 + col] = z1;
        }
    }

    if (ce.doneCtr) {
        __threadfence();         // agent-scope: drain stores, make visible
        __syncthreads();         // all threads' fences precede the signal
        if (threadIdx.x == 0)
            __hip_atomic_fetch_add(ce.doneCtr, 1u, __ATOMIC_RELEASE,
                                   __HIP_MEMORY_SCOPE_AGENT);
    }
}

__global__ __launch_bounds__(512, 2)
void proj_mfma(PStage ps, int tcShift)
{
    __shared__ __align__(16) unsigned short smem[8 * 16 * 136];
    proj_body(ps.c[0], blockIdx.x, tcShift, (tab_t*)smem);
}

// ---------------- LSTM recurrence cell (device body, v12 math) -----------
struct Cell {
    const float* xw;
    const unsigned short* rf;
    float* hs;
    float* cs;
    unsigned int* hout;        // packed h_hi | h_lo<<16
    unsigned int* waitCtr;     // spin until *waitCtr >= waitTarget (v14)
    unsigned int waitTarget;
    int init;
};

__device__ __forceinline__ void lstm_body(const Cell& ce, int blk, int Tc,
                                          tab_t* __restrict__ htab)
{
    // v14: wait for same-launch projL12 producers. Deadlock-free by
    // capacity: spinner blocks <= 96 < 256 CUs, producers never wait.
    if (ce.waitTarget) {
        while (__hip_atomic_load(ce.waitCtr, __ATOMIC_ACQUIRE,
                                 __HIP_MEMORY_SCOPE_AGENT) < ce.waitTarget)
            __builtin_amdgcn_s_sleep(2);
    }

    const float* __restrict__ xw = ce.xw;
    const unsigned short* __restrict__ Rf = ce.rf;
    float* __restrict__ h_state = ce.hs;
    float* __restrict__ c_state = ce.cs;
    unsigned int* __restrict__ h_out = ce.hout;
    const int init = ce.init;

    const int tid  = threadIdx.x;
    const int lane = tid & 63;
    const int w    = tid >> 6;
    const int m    = lane & 15;
    const int quad = lane >> 4;

    short8 bf[4][4][2];
    #pragma unroll
    for (int g = 0; g < 4; ++g)
        #pragma unroll
        for (int kt = 0; kt < 4; ++kt)
            #pragma unroll
            for (int pp = 0; pp < 2; ++pp)
                bf[g][kt][pp] = *(const short8*)(
                    Rf + ((size_t)((((w * 4 + g) * 4 + kt) * 2) + pp) * 64 + lane) * 8);

    const int unit = w * 16 + m;
    const int s0   = 2 * quad;
    const int s1   = s0 + 1;

    float c0 = 0.f, c1 = 0.f;
    if (!init) {
        c0 = c_state[(blk * SEQS + s0) * UNITS + unit];
        c1 = c_state[(blk * SEQS + s1) * UNITS + unit];
    }
    {
        int uu = tid & 127;
        #pragma unroll
        for (int i = 0; i < 2; ++i) {
            int s = (tid >> 7) + i * 4;
            float hv = init ? 0.f : h_state[(blk * SEQS + s) * UNITS + uu];
            unsigned short hi = f2bf(hv);
            htab[0][2 * s][uu]     = hi;
            htab[0][2 * s + 1][uu] = f2bf(hv - bf2f(hi));
        }
    }
    __syncthreads();

    const float* xw0 = xw + (size_t)(blk * SEQS + s0) * Tc * U4 + unit;
    const float* xw1 = xw + (size_t)(blk * SEQS + s1) * Tc * U4 + unit;

    float xa[8], xb[8];
    #pragma unroll
    for (int g = 0; g < 4; ++g) {
        xa[g]     = xw0[g * UNITS];
        xa[4 + g] = xw1[g * UNITS];
    }
    {
        const size_t o1 = (size_t)((Tc > 1) ? 1 : 0) * U4;
        #pragma unroll
        for (int g = 0; g < 4; ++g) {
            xb[g]     = xw0[o1 + g * UNITS];
            xb[4 + g] = xw1[o1 + g * UNITS];
        }
    }

    float hl0 = 0.f, hl1 = 0.f;

    auto STEP = [&](int t, int p, float (&xc)[8]) {
        short8 af[4];
        #pragma unroll
        for (int kt = 0; kt < 4; ++kt)
            af[kt] = *(const short8*)(&htab[p][m][kt * 32 + quad * 8]);

        f32x4 C0 = {xc[0], 0.f, xc[4], 0.f};
        f32x4 C1 = {xc[1], 0.f, xc[5], 0.f};
        f32x4 C2 = {xc[2], 0.f, xc[6], 0.f};
        f32x4 C3 = {xc[3], 0.f, xc[7], 0.f};

        int tp = t + 2; if (tp >= Tc) tp = Tc - 1;
        const size_t off = (size_t)tp * U4;
        #pragma unroll
        for (int g = 0; g < 4; ++g) {
            xc[g]     = xw0[off + g * UNITS];
            xc[4 + g] = xw1[off + g * UNITS];
        }

        __builtin_amdgcn_s_setprio(1);
        #pragma unroll
        for (int kt = 0; kt < 4; ++kt) {
            #pragma unroll
            for (int pp = 0; pp < 2; ++pp) {
                MFMA_BF16(C0, af[kt], bf[0][kt][pp]);
                MFMA_BF16(C1, af[kt], bf[1][kt][pp]);
            }
        }
        float zi0 = C0.x + C0.y, zi1 = C0.z + C0.w;
        float zf0 = C1.x + C1.y, zf1 = C1.z + C1.w;
        float iv0 = sigm(zi0), iv1 = sigm(zi1);
        float fv0 = sigm(zf0), fv1 = sigm(zf1);

        #pragma unroll
        for (int kt = 0; kt < 4; ++kt) {
            #pragma unroll
            for (int pp = 0; pp < 2; ++pp) {
                MFMA_BF16(C2, af[kt], bf[2][kt][pp]);
                MFMA_BF16(C3, af[kt], bf[3][kt][pp]);
            }
        }
        __builtin_amdgcn_s_setprio(0);

        float zg0 = C2.x + C2.y, zg1 = C2.z + C2.w;
        float zo0 = C3.x + C3.y, zo1 = C3.z + C3.w;

        float gv0 = tanh_fast(zg0), ov0 = sigm(zo0);
        c0 = __builtin_fmaf(fv0, c0, iv0 * gv0);
        float hv0 = ov0 * tanh_fast(c0);

        float gv1 = tanh_fast(zg1), ov1 = sigm(zo1);
        c1 = __builtin_fmaf(fv1, c1, iv1 * gv1);
        float hv1 = ov1 * tanh_fast(c1);

        hl0 = hv0; hl1 = hv1;

        unsigned short hi0 = f2bf(hv0);
        unsigned short lo0 = f2bf(hv0 - bf2f(hi0));
        htab[p ^ 1][4 * quad + 0][unit] = hi0;
        htab[p ^ 1][4 * quad + 1][unit] = lo0;
        unsigned short hi1 = f2bf(hv1);
        unsigned short lo1 = f2bf(hv1 - bf2f(hi1));
        htab[p ^ 1][4 * quad + 2][unit] = hi1;
        htab[p ^ 1][4 * quad + 3][unit] = lo1;

        if (h_out) {
            h_out[((size_t)(blk * SEQS + s0) * Tc + t) * UNITS + unit] =
                (unsigned int)hi0 | ((unsigned int)lo0 << 16);
            h_out[((size_t)(blk * SEQS + s1) * Tc + t) * UNITS + unit] =
                (unsigned int)hi1 | ((unsigned int)lo1 << 16);
        }
        barrier_lds_only();
    };

    #pragma unroll 1
    for (int t = 0; t < Tc; t += 2) {
        STEP(t,     0, xa);
        STEP(t + 1, 1, xb);
    }

    c_state[(blk * SEQS + s0) * UNITS + unit] = c0;
    c_state[(blk * SEQS + s1) * UNITS + unit] = c1;
    h_state[(blk * SEQS + s0) * UNITS + unit] = hl0;
    h_state[(blk * SEQS + s1) * UNITS + unit] = hl1;
}

// ---------------- fused stage (v14) --------------------------------------
// ONE launch per stage: [projL12 producers | proj0(chunk s+1) | lstm cells].
// lstm cells with lam>=1 spin on the per-(stage,lam) counter their xw
// producer signals. Block order puts producers at low blockIdx, but
// correctness does NOT rely on dispatch order (capacity argument above).
struct FusedArgs {
    Cell  lc[3];
    PCell pl[2];
    PCell pc;
    int n_lstm, n_projL, has_proj0, pad_;
};

__global__ __launch_bounds__(512, 2)
void stage_fused(FusedArgs fa, int Tc, int tcShift, int pg)
{
    __shared__ __align__(16) unsigned short smem[8 * 16 * 136];
    int bx = blockIdx.x;
    int npl = fa.n_projL * pg;
    if (bx < npl) {
        proj_body(fa.pl[bx / pg], bx % pg, tcShift, (tab_t*)smem);
        return;
    }
    bx -= npl;
    if (fa.has_proj0) {
        if (bx < pg) { proj_body(fa.pc, bx, tcShift, (tab_t*)smem); return; }
        bx -= pg;
    }
    lstm_body(fa.lc[bx >> 5], bx & 31, Tc, (tab_t*)smem);
}

// ---------------- dense head ----------------
__global__ __launch_bounds__(256)
void dense_head(const float* __restrict__ h2, const float* __restrict__ Wd,
                const float* __restrict__ bd, float* __restrict__ out)
{
    int b = threadIdx.x;
    float acc[6];
    #pragma unroll
    for (int o = 0; o < 6; ++o) acc[o] = bd[o];
    #pragma unroll 4
    for (int k = 0; k < UNITS; ++k) {
        float hv = h2[b * UNITS + k];
        #pragma unroll
        for (int o = 0; o < 6; ++o)
            acc[o] = __builtin_fmaf(hv, Wd[k * 6 + o], acc[o]);
    }
    #pragma unroll
    for (int o = 0; o < 6; ++o) out[b * 6 + o] = acc[o];
}

extern "C" void kernel_launch(void* const* d_in, const int* in_sizes, int n_in,
                              void* d_out, int out_size, void* d_ws, size_t ws_size,
                              hipStream_t stream)
{
    (void)in_sizes; (void)n_in; (void)out_size;
    const float* x  = (const float*)d_in[0];
    const float* Ws[3] = {(const float*)d_in[1], (const float*)d_in[4], (const float*)d_in[7]};
    const float* Rs[3] = {(const float*)d_in[2], (const float*)d_in[5], (const float*)d_in[8]};
    const float* bs[3] = {(const float*)d_in[3], (const float*)d_in[6], (const float*)d_in[9]};
    const float* Wd = (const float*)d_in[10];
    const float* bd = (const float*)d_in[11];
    float* out = (float*)d_out;

    // ws: 4 xw (xw0 x2 parity, xw1, xw2) + 4 hc (2 lam x 2 parity, u32) +
    // hs/cs + Rf + Wf + 64 counters.
    // per-Tc bytes = 4*BATCH*512*4 + 4*BATCH*128*4 = Tc*2621440.
    int tcShift = 6;
    while (tcShift > 2) {
        size_t need = ((size_t)1 << tcShift) * 2621440u + 2359552u;
        if (need <= ws_size) break;
        --tcShift;
    }
    const int Tc = 1 << tcShift;
    const int nCh = TSEQ / Tc;
    const int projGrid = BATCH * Tc / 64;

    const size_t xwStride = (size_t)BATCH * Tc * U4;
    const size_t hcStride = (size_t)BATCH * Tc * UNITS;

    float* xw = (float*)d_ws;                                    // 4 x xwStride
    unsigned int* hc = (unsigned int*)(xw + 4 * xwStride);       // 4 x hcStride
    float* hs = (float*)(hc + 4 * hcStride);                     // 3 x [B][128]
    float* cs = hs + 3 * BATCH * UNITS;
    unsigned short* Rf = (unsigned short*)(cs + 3 * BATCH * UNITS); // 3 x 131072
    unsigned short* Wf = Rf + 3 * 131072;                        // 3 x 131072
    unsigned int* ctrs = (unsigned int*)(Wf + 3 * 131072);       // 64 slots

    rw_frag<<<384, 256, 0, stream>>>(Rs[0], Rs[1], Rs[2], Ws[0], Ws[1], Ws[2],
                                     Rf, Wf, ctrs);

    // prologue: layer-0 proj of chunk 0 into xw[parity 0]
    {
        PStage ps{};
        ps.c[0].in = x; ps.c[0].out = xw; ps.c[0].wf = Wf; ps.c[0].bias = bs[0];
        ps.c[0].doneCtr = nullptr;
        ps.c[0].sB = TSEQ * FEAT; ps.c[0].sT = FEAT; ps.c[0].t0 = 0;
        ps.c[0].K = FEAT; ps.c[0].packed = 0;
        proj_mfma<<<dim3(projGrid), 512, 0, stream>>>(ps, tcShift);
    }

    // anti-diagonal wavefront over (chunk c, layer lam), c + lam = s.
    for (int s = 0; s <= nCh + 1; ++s) {
        int lo = s - (nCh - 1); if (lo < 0) lo = 0;
        int hi = (s < 2) ? s : 2;
        if (lo > hi) continue;

        FusedArgs fa{};

        // projL12 producers (consume hc parity written last stage)
        int pn = 0;
        int plo = (lo > 1) ? lo : 1;
        for (int lam = plo; lam <= hi; ++lam) {
            int c = s - lam;
            fa.pl[pn].in      = hc + (size_t)((lam - 1) * 2 + (c & 1)) * hcStride;
            fa.pl[pn].out     = xw + (size_t)(1 + lam) * xwStride;  // lam1->2, lam2->3
            fa.pl[pn].wf      = Wf + (size_t)lam * 131072;
            fa.pl[pn].bias    = bs[lam];
            fa.pl[pn].doneCtr = ctrs + (s * 2 + (lam - 1));
            fa.pl[pn].sB      = Tc * UNITS;
            fa.pl[pn].sT      = UNITS;
            fa.pl[pn].t0      = 0;
            fa.pl[pn].K       = UNITS;
            fa.pl[pn].packed  = 1;
            ++pn;
        }
        fa.n_projL = pn;

        // lstm cells
        int n = 0;
        for (int lam = lo; lam <= hi; ++lam) {
            int c = s - lam;
            fa.lc[n].xw   = (lam == 0) ? xw + (size_t)(c & 1) * xwStride
                                       : xw + (size_t)(1 + lam) * xwStride;
            fa.lc[n].rf   = Rf + (size_t)lam * 131072;
            fa.lc[n].hs   = hs + lam * BATCH * UNITS;
            fa.lc[n].cs   = cs + lam * BATCH * UNITS;
            fa.lc[n].hout = (lam < 2)
                ? (hc + (size_t)(lam * 2 + (c & 1)) * hcStride) : nullptr;
            fa.lc[n].waitCtr    = (lam >= 1) ? (ctrs + (s * 2 + (lam - 1))) : nullptr;
            fa.lc[n].waitTarget = (lam >= 1) ? (unsigned int)projGrid : 0u;
            fa.lc[n].init = (c == 0) ? 1 : 0;
            ++n;
        }
        fa.n_lstm = n;

        // hidden layer-0 proj for chunk s+1
        int c0 = s + 1;
        fa.has_proj0 = (c0 <= nCh - 1) ? 1 : 0;
        if (fa.has_proj0) {
            fa.pc.in = x; fa.pc.out = xw + (size_t)(c0 & 1) * xwStride;
            fa.pc.wf = Wf; fa.pc.bias = bs[0]; fa.pc.doneCtr = nullptr;
            fa.pc.sB = TSEQ * FEAT; fa.pc.sT = FEAT; fa.pc.t0 = c0 * Tc;
            fa.pc.K = FEAT; fa.pc.packed = 0;
        }

        int gridx = pn * projGrid + (fa.has_proj0 ? projGrid : 0) + n * NBLK;
        stage_fused<<<dim3(gridx), 512, 0, stream>>>(fa, Tc, tcShift, projGrid);
    }

    dense_head<<<1, 256, 0, stream>>>(hs + 2 * BATCH * UNITS, Wd, bd, out);
}

// Round 12
// 1124.667 us; speedup vs baseline: 2.0870x; 2.0870x over previous
//
#include <hip/hip_runtime.h>
#include <cstdint>
#include <cstddef>

#define U4    512   // 4*U
#define UNITS 128
#define BATCH 256
#define TSEQ  512
#define FEAT  64
#define SEQS  8                  // sequences per lstm cell block (fills 16 A-rows)
#define NBLK  (BATCH / SEQS)     // 32 blocks per lstm cell

typedef short short8 __attribute__((ext_vector_type(8)));
typedef float f32x4  __attribute__((ext_vector_type(4)));
typedef unsigned short tab_t[16][136];

// MFMA inline asm ("a" on B keeps the AGPR-resident fragment set readable
// in place; perf-equivalent to builtin per R7/R8 but pins allocation).
#define MFMA_BF16(C, A, B) \
    asm("v_mfma_f32_16x16x32_bf16 %0, %1, %2, %0" : "+v"(C) : "v"(A), "a"(B))

// Raw barrier draining ONLY LDS (v8).
__device__ __forceinline__ void barrier_lds_only() {
    __builtin_amdgcn_sched_barrier(0);
    asm volatile("s_waitcnt lgkmcnt(0)" ::: "memory");
    __builtin_amdgcn_s_barrier();
    __builtin_amdgcn_sched_barrier(0);
}

// ---------------- fast activations (fp32, ~1e-7 rel err) ----------------
__device__ __forceinline__ float sigm(float x) {
    float e = __expf(-x);
    return __fdividef(1.0f, 1.0f + e);
}
__device__ __forceinline__ float tanh_fast(float x) {
    float e = __expf(2.0f * x);
    return 1.0f - __fdividef(2.0f, e + 1.0f);
}

// ---------------- bf16 split helpers (RNE) ----------------
__device__ __forceinline__ unsigned short f2bf(float f) {
    unsigned u = __float_as_uint(f);
    unsigned r = u + 0x7FFFu + ((u >> 16) & 1u);
    return (unsigned short)(r >> 16);
}
__device__ __forceinline__ float bf2f(unsigned short h) {
    return __uint_as_float(((unsigned)h) << 16);
}

// ---------------- R & W -> bf16 hi/lo MFMA B-fragments (fused launch) -----
__global__ __launch_bounds__(256)
void rw_frag(const float* __restrict__ R0, const float* __restrict__ R1,
             const float* __restrict__ R2,
             const float* __restrict__ W0, const float* __restrict__ W1,
             const float* __restrict__ W2,
             unsigned short* __restrict__ Rf, unsigned short* __restrict__ Wf)
{
    if (blockIdx.x < 192) {
        int gid = blockIdx.x * 256 + threadIdx.x;    // 3 * 16384
        int l    = gid >> 14;
        int r    = gid & 16383;
        int lane = r & 63;
        int fi   = r >> 6;
        int pass = fi & 1;
        int kt   = (fi >> 1) & 3;
        int gate = (fi >> 3) & 3;
        int w    = fi >> 5;
        const float* R = (l == 0) ? R0 : (l == 1) ? R1 : R2;

        int col = gate * UNITS + w * 16 + (lane & 15);
        int k0  = kt * 32 + (lane >> 4) * 8;
        short8 v;
        #pragma unroll
        for (int j = 0; j < 8; ++j) {
            float x = R[(size_t)(k0 + j) * U4 + col];
            unsigned short hi = f2bf(x);
            unsigned short s = pass ? f2bf(x - bf2f(hi)) : hi;
            v[j] = (short)s;
        }
        *(short8*)(Rf + (size_t)gid * 8) = v;
    } else {
        int gid = (blockIdx.x - 192) * 256 + threadIdx.x;
        int l    = gid >> 14;
        int r    = gid & 16383;
        int lane = r & 63;
        int fi   = r >> 6;
        int pass = fi & 1;
        int kt   = (fi >> 1) & 3;
        int nt   = fi >> 3;
        const float* W = (l == 0) ? W0 : (l == 1) ? W1 : W2;
        const int K = (l == 0) ? FEAT : UNITS;

        int col = nt * 16 + (lane & 15);
        int k0  = kt * 32 + (lane >> 4) * 8;
        short8 v;
        #pragma unroll
        for (int j = 0; j < 8; ++j) {
            float x = (k0 + j < K) ? W[(size_t)(k0 + j) * U4 + col] : 0.f;
            unsigned short hi = f2bf(x);
            unsigned short s = pass ? f2bf(x - bf2f(hi)) : hi;
            v[j] = (short)s;
        }
        *(short8*)(Wf + (size_t)gid * 8) = v;
    }
}

// ---------------- projection cell (device body, v13) ---------------------
// packed=1: input is u32 (h_hi | h_lo<<16) from lstm -> direct unpack,
// no RNE split. packed=0: fp32 input (layer 0 / x), split here.
struct PCell {
    const void* in;
    float* out;
    const unsigned short* wf;
    const float* bias;
    int sB, sT, t0, K, packed, pad_;
};
struct PStage { PCell c[2]; };

__device__ __forceinline__ void proj_body(const PCell& ce, int bx, int tcShift,
                                          tab_t* __restrict__ atab)
{
    const int tid  = threadIdx.x;
    const int lane = tid & 63;
    const int w    = tid >> 6;
    const int m    = lane & 15;
    const int quad = lane >> 4;
    const int TcMask = (1 << tcShift) - 1;
    const int m0 = bx * 64;

    short8 bf[4][4][2];
    #pragma unroll
    for (int nt = 0; nt < 4; ++nt)
        #pragma unroll
        for (int kt = 0; kt < 4; ++kt)
            #pragma unroll
            for (int pp = 0; pp < 2; ++pp)
                bf[nt][kt][pp] = *(const short8*)(
                    ce.wf + ((size_t)((((w * 4 + nt) * 4 + kt) * 2) + pp) * 64 + lane) * 8);

    if (ce.packed) {
        const unsigned int* __restrict__ inp = (const unsigned int*)ce.in;
        #pragma unroll
        for (int rep = 0; rep < 16; ++rep) {
            int idx = rep * 512 + tid;
            int row = idx >> 7;
            int k   = idx & 127;
            int rg  = m0 + row;
            int b = rg >> tcShift, tc = rg & TcMask;
            unsigned int u = inp[(size_t)b * ce.sB + (size_t)(ce.t0 + tc) * ce.sT + k];
            atab[row >> 3][2 * (row & 7)][k]     = (unsigned short)(u & 0xFFFFu);
            atab[row >> 3][2 * (row & 7) + 1][k] = (unsigned short)(u >> 16);
        }
    } else {
        const float* __restrict__ inp = (const float*)ce.in;
        #pragma unroll
        for (int rep = 0; rep < 16; ++rep) {
            int idx = rep * 512 + tid;
            int row = idx >> 7;
            int k   = idx & 127;
            int rg  = m0 + row;
            int b = rg >> tcShift, tc = rg & TcMask;
            float x = 0.f;
            if (k < ce.K)
                x = inp[(size_t)b * ce.sB + (size_t)(ce.t0 + tc) * ce.sT + k];
            unsigned short hi = f2bf(x);
            atab[row >> 3][2 * (row & 7)][k]     = hi;
            atab[row >> 3][2 * (row & 7) + 1][k] = f2bf(x - bf2f(hi));
        }
    }
    __syncthreads();

    float bb[4];
    #pragma unroll
    for (int nt = 0; nt < 4; ++nt) bb[nt] = ce.bias[w * 64 + nt * 16 + m];

    float* __restrict__ outp = ce.out;
    #pragma unroll 1
    for (int r = 0; r < 8; ++r) {
        short8 af[4];
        #pragma unroll
        for (int kt = 0; kt < 4; ++kt)
            af[kt] = *(const short8*)(&atab[r][m][kt * 32 + quad * 8]);

        f32x4 C[4];
        #pragma unroll
        for (int nt = 0; nt < 4; ++nt) C[nt] = f32x4{0.f, 0.f, 0.f, 0.f};

        #pragma unroll
        for (int kt = 0; kt < 4; ++kt)
            #pragma unroll
            for (int pp = 0; pp < 2; ++pp)
                #pragma unroll
                for (int nt = 0; nt < 4; ++nt)
                    MFMA_BF16(C[nt], af[kt], bf[nt][kt][pp]);

        int row0 = m0 + r * 8 + 2 * quad;
        #pragma unroll
        for (int nt = 0; nt < 4; ++nt) {
            float z0 = C[nt].x + C[nt].y + bb[nt];
            float z1 = C[nt].z + C[nt].w + bb[nt];
            int col = w * 64 + nt * 16 + m;
            outp[(size_t)row0 * U4 + col]       = z0;
            outp[(size_t)(row0 + 1) * U4 + col] = z1;
        }
    }
}

__global__ __launch_bounds__(512, 2)
void proj_mfma(PStage ps, int tcShift)
{
    __shared__ __align__(16) unsigned short smem[8 * 16 * 136];
    proj_body(ps.c[blockIdx.y], blockIdx.x, tcShift, (tab_t*)smem);
}

// ---------------- LSTM recurrence cell (device body, v12 math) -----------
struct Cell {
    const float* xw;
    const unsigned short* rf;
    float* hs;
    float* cs;
    unsigned int* hout;    // packed h_hi | h_lo<<16 (v13)
    int init;
    int pad_;
};

__device__ __forceinline__ void lstm_body(const Cell& ce, int blk, int Tc,
                                          tab_t* __restrict__ htab)
{
    const float* __restrict__ xw = ce.xw;
    const unsigned short* __restrict__ Rf = ce.rf;
    float* __restrict__ h_state = ce.hs;
    float* __restrict__ c_state = ce.cs;
    unsigned int* __restrict__ h_out = ce.hout;
    const int init = ce.init;

    const int tid  = threadIdx.x;
    const int lane = tid & 63;
    const int w    = tid >> 6;
    const int m    = lane & 15;
    const int quad = lane >> 4;

    short8 bf[4][4][2];
    #pragma unroll
    for (int g = 0; g < 4; ++g)
        #pragma unroll
        for (int kt = 0; kt < 4; ++kt)
            #pragma unroll
            for (int pp = 0; pp < 2; ++pp)
                bf[g][kt][pp] = *(const short8*)(
                    Rf + ((size_t)((((w * 4 + g) * 4 + kt) * 2) + pp) * 64 + lane) * 8);

    const int unit = w * 16 + m;
    const int s0   = 2 * quad;
    const int s1   = s0 + 1;

    float c0 = 0.f, c1 = 0.f;
    if (!init) {
        c0 = c_state[(blk * SEQS + s0) * UNITS + unit];
        c1 = c_state[(blk * SEQS + s1) * UNITS + unit];
    }
    {
        int uu = tid & 127;
        #pragma unroll
        for (int i = 0; i < 2; ++i) {
            int s = (tid >> 7) + i * 4;
            float hv = init ? 0.f : h_state[(blk * SEQS + s) * UNITS + uu];
            unsigned short hi = f2bf(hv);
            htab[0][2 * s][uu]     = hi;
            htab[0][2 * s + 1][uu] = f2bf(hv - bf2f(hi));
        }
    }
    __syncthreads();

    const float* xw0 = xw + (size_t)(blk * SEQS + s0) * Tc * U4 + unit;
    const float* xw1 = xw + (size_t)(blk * SEQS + s1) * Tc * U4 + unit;

    float xa[8], xb[8];
    #pragma unroll
    for (int g = 0; g < 4; ++g) {
        xa[g]     = xw0[g * UNITS];
        xa[4 + g] = xw1[g * UNITS];
    }
    {
        const size_t o1 = (size_t)((Tc > 1) ? 1 : 0) * U4;
        #pragma unroll
        for (int g = 0; g < 4; ++g) {
            xb[g]     = xw0[o1 + g * UNITS];
            xb[4 + g] = xw1[o1 + g * UNITS];
        }
    }

    float hl0 = 0.f, hl1 = 0.f;

    auto STEP = [&](int t, int p, float (&xc)[8]) {
        short8 af[4];
        #pragma unroll
        for (int kt = 0; kt < 4; ++kt)
            af[kt] = *(const short8*)(&htab[p][m][kt * 32 + quad * 8]);

        f32x4 C0 = {xc[0], 0.f, xc[4], 0.f};
        f32x4 C1 = {xc[1], 0.f, xc[5], 0.f};
        f32x4 C2 = {xc[2], 0.f, xc[6], 0.f};
        f32x4 C3 = {xc[3], 0.f, xc[7], 0.f};

        int tp = t + 2; if (tp >= Tc) tp = Tc - 1;
        const size_t off = (size_t)tp * U4;
        #pragma unroll
        for (int g = 0; g < 4; ++g) {
            xc[g]     = xw0[off + g * UNITS];
            xc[4 + g] = xw1[off + g * UNITS];
        }

        __builtin_amdgcn_s_setprio(1);
        #pragma unroll
        for (int kt = 0; kt < 4; ++kt) {
            #pragma unroll
            for (int pp = 0; pp < 2; ++pp) {
                MFMA_BF16(C0, af[kt], bf[0][kt][pp]);
                MFMA_BF16(C1, af[kt], bf[1][kt][pp]);
            }
        }
        float zi0 = C0.x + C0.y, zi1 = C0.z + C0.w;
        float zf0 = C1.x + C1.y, zf1 = C1.z + C1.w;
        float iv0 = sigm(zi0), iv1 = sigm(zi1);
        float fv0 = sigm(zf0), fv1 = sigm(zf1);

        #pragma unroll
        for (int kt = 0; kt < 4; ++kt) {
            #pragma unroll
            for (int pp = 0; pp < 2; ++pp) {
                MFMA_BF16(C2, af[kt], bf[2][kt][pp]);
                MFMA_BF16(C3, af[kt], bf[3][kt][pp]);
            }
        }
        __builtin_amdgcn_s_setprio(0);

        float zg0 = C2.x + C2.y, zg1 = C2.z + C2.w;
        float zo0 = C3.x + C3.y, zo1 = C3.z + C3.w;

        float gv0 = tanh_fast(zg0), ov0 = sigm(zo0);
        c0 = __builtin_fmaf(fv0, c0, iv0 * gv0);
        float hv0 = ov0 * tanh_fast(c0);

        float gv1 = tanh_fast(zg1), ov1 = sigm(zo1);
        c1 = __builtin_fmaf(fv1, c1, iv1 * gv1);
        float hv1 = ov1 * tanh_fast(c1);

        hl0 = hv0; hl1 = hv1;

        unsigned short hi0 = f2bf(hv0);
        unsigned short lo0 = f2bf(hv0 - bf2f(hi0));
        htab[p ^ 1][4 * quad + 0][unit] = hi0;
        htab[p ^ 1][4 * quad + 1][unit] = lo0;
        unsigned short hi1 = f2bf(hv1);
        unsigned short lo1 = f2bf(hv1 - bf2f(hi1));
        htab[p ^ 1][4 * quad + 2][unit] = hi1;
        htab[p ^ 1][4 * quad + 3][unit] = lo1;

        if (h_out) {
            h_out[((size_t)(blk * SEQS + s0) * Tc + t) * UNITS + unit] =
                (unsigned int)hi0 | ((unsigned int)lo0 << 16);
            h_out[((size_t)(blk * SEQS + s1) * Tc + t) * UNITS + unit] =
                (unsigned int)hi1 | ((unsigned int)lo1 << 16);
        }
        barrier_lds_only();
    };

    #pragma unroll 1
    for (int t = 0; t < Tc; t += 2) {
        STEP(t,     0, xa);
        STEP(t + 1, 1, xb);
    }

    c_state[(blk * SEQS + s0) * UNITS + unit] = c0;
    c_state[(blk * SEQS + s1) * UNITS + unit] = c1;
    h_state[(blk * SEQS + s0) * UNITS + unit] = hl0;
    h_state[(blk * SEQS + s1) * UNITS + unit] = hl1;
}

// ---------------- fused stage: lstm cells + hidden layer-0 proj ----------
// v13 (verified 1113us): layer-0 proj (chunk s+1) has no lstm dependency ->
// rides in the SAME launch as the stage's lstm cells and fills idle CUs.
// projL12 stays a SEPARATE prior launch: v14's same-launch spin-sync
// regressed 2.1x (spinner blocks pin CU slots through the proj phase;
// stream-level serialization of a 12us launch is cheaper than any
// same-launch spin dependency at this block count).
struct FusedArgs {
    Cell lc[3];
    PCell pc;
    int n_lstm;
    int has_proj;
};

__global__ __launch_bounds__(512, 2)
void stage_fused(FusedArgs fa, int Tc, int tcShift)
{
    __shared__ __align__(16) unsigned short smem[8 * 16 * 136];
    int bx = blockIdx.x;
    if (bx < fa.n_lstm * NBLK)
        lstm_body(fa.lc[bx >> 5], bx & 31, Tc, (tab_t*)smem);
    else
        proj_body(fa.pc, bx - fa.n_lstm * NBLK, tcShift, (tab_t*)smem);
}

// ---------------- dense head ----------------
__global__ __launch_bounds__(256)
void dense_head(const float* __restrict__ h2, const float* __restrict__ Wd,
                const float* __restrict__ bd, float* __restrict__ out)
{
    int b = threadIdx.x;
    float acc[6];
    #pragma unroll
    for (int o = 0; o < 6; ++o) acc[o] = bd[o];
    #pragma unroll 4
    for (int k = 0; k < UNITS; ++k) {
        float hv = h2[b * UNITS + k];
        #pragma unroll
        for (int o = 0; o < 6; ++o)
            acc[o] = __builtin_fmaf(hv, Wd[k * 6 + o], acc[o]);
    }
    #pragma unroll
    for (int o = 0; o < 6; ++o) out[b * 6 + o] = acc[o];
}

extern "C" void kernel_launch(void* const* d_in, const int* in_sizes, int n_in,
                              void* d_out, int out_size, void* d_ws, size_t ws_size,
                              hipStream_t stream)
{
    (void)in_sizes; (void)n_in; (void)out_size;
    const float* x  = (const float*)d_in[0];
    const float* Ws[3] = {(const float*)d_in[1], (const float*)d_in[4], (const float*)d_in[7]};
    const float* Rs[3] = {(const float*)d_in[2], (const float*)d_in[5], (const float*)d_in[8]};
    const float* bs[3] = {(const float*)d_in[3], (const float*)d_in[6], (const float*)d_in[9]};
    const float* Wd = (const float*)d_in[10];
    const float* bd = (const float*)d_in[11];
    float* out = (float*)d_out;

    // ws: 4 xw buffers (xw0 x2 parity, xw1, xw2) + 2 hc (packed u32) +
    // hs/cs + Rf + Wf.  per-Tc bytes = 4*524288 + 2*131072 = 2359296.
    int tcShift = 6;
    while (tcShift > 2) {
        size_t need = ((size_t)1 << tcShift) * 2359296u + 2359296u;
        if (need <= ws_size) break;
        --tcShift;
    }
    const int Tc = 1 << tcShift;
    const int nCh = TSEQ / Tc;
    const int projGrid = BATCH * Tc / 64;

    const size_t xwStride = (size_t)BATCH * Tc * U4;
    const size_t hcStride = (size_t)BATCH * Tc * UNITS;

    float* xw = (float*)d_ws;                                    // 4 x xwStride
    unsigned int* hc = (unsigned int*)(xw + 4 * xwStride);       // 2 x hcStride
    float* hs = (float*)(hc + 2 * hcStride);                     // 3 x [B][128]
    float* cs = hs + 3 * BATCH * UNITS;
    unsigned short* Rf = (unsigned short*)(cs + 3 * BATCH * UNITS); // 3 x 131072
    unsigned short* Wf = Rf + 3 * 131072;                        // 3 x 131072

    rw_frag<<<384, 256, 0, stream>>>(Rs[0], Rs[1], Rs[2], Ws[0], Ws[1], Ws[2], Rf, Wf);

    // prologue: layer-0 proj of chunk 0 into xw[parity 0]
    {
        PStage ps{};
        ps.c[0].in = x; ps.c[0].out = xw; ps.c[0].wf = Wf; ps.c[0].bias = bs[0];
        ps.c[0].sB = TSEQ * FEAT; ps.c[0].sT = FEAT; ps.c[0].t0 = 0;
        ps.c[0].K = FEAT; ps.c[0].packed = 0;
        proj_mfma<<<dim3(projGrid, 1), 512, 0, stream>>>(ps, tcShift);
    }

    // anti-diagonal wavefront over (chunk c, layer lam), c + lam = s.
    for (int s = 0; s <= nCh + 1; ++s) {
        int lo = s - (nCh - 1); if (lo < 0) lo = 0;
        int hi = (s < 2) ? s : 2;
        if (lo > hi) continue;

        // layers 1-2 proj (depends on hc written last stage)
        PStage ps{};
        int pn = 0;
        int plo = (lo > 1) ? lo : 1;
        for (int lam = plo; lam <= hi; ++lam) {
            ps.c[pn].in   = hc + (size_t)(lam - 1) * hcStride;
            ps.c[pn].out  = xw + (size_t)(1 + lam) * xwStride;   // lam1->slot2, lam2->slot3
            ps.c[pn].wf   = Wf + (size_t)lam * 131072;
            ps.c[pn].bias = bs[lam];
            ps.c[pn].sB   = Tc * UNITS;
            ps.c[pn].sT   = UNITS;
            ps.c[pn].t0   = 0;
            ps.c[pn].K    = UNITS;
            ps.c[pn].packed = 1;
            ++pn;
        }
        if (pn) proj_mfma<<<dim3(projGrid, pn), 512, 0, stream>>>(ps, tcShift);

        // fused: lstm cells + hidden layer-0 proj for chunk s+1
        FusedArgs fa{};
        int n = 0;
        for (int lam = lo; lam <= hi; ++lam) {
            int c = s - lam;
            fa.lc[n].xw   = (lam == 0) ? xw + (size_t)(c & 1) * xwStride
                                       : xw + (size_t)(1 + lam) * xwStride;
            fa.lc[n].rf   = Rf + (size_t)lam * 131072;
            fa.lc[n].hs   = hs + lam * BATCH * UNITS;
            fa.lc[n].cs   = cs + lam * BATCH * UNITS;
            fa.lc[n].hout = (lam < 2) ? (hc + (size_t)lam * hcStride) : nullptr;
            fa.lc[n].init = (c == 0) ? 1 : 0;
            ++n;
        }
        fa.n_lstm = n;
        int c0 = s + 1;
        fa.has_proj = (c0 <= nCh - 1) ? 1 : 0;
        if (fa.has_proj) {
            fa.pc.in = x; fa.pc.out = xw + (size_t)(c0 & 1) * xwStride;
            fa.pc.wf = Wf; fa.pc.bias = bs[0];
            fa.pc.sB = TSEQ * FEAT; fa.pc.sT = FEAT; fa.pc.t0 = c0 * Tc;
            fa.pc.K = FEAT; fa.pc.packed = 0;
        }
        int gridx = n * NBLK + (fa.has_proj ? projGrid : 0);
        stage_fused<<<dim3(gridx), 512, 0, stream>>>(fa, Tc, tcShift);
    }

    dense_head<<<1, 256, 0, stream>>>(hs + 2 * BATCH * UNITS, Wd, bd, out);
}